// Round 1
// baseline (863.878 us; speedup 1.0000x reference)
//
#include <hip/hip_runtime.h>

#define B_ 4
#define L_ 2048
#define E_ 512
#define H_ 8
#define D_ 64
#define NEGV (-1e9f)

typedef short s8v __attribute__((ext_vector_type(8)));
typedef float f4v __attribute__((ext_vector_type(4)));

static __device__ __forceinline__ unsigned short f2bf(float f) {
    union { float f; unsigned u; } v; v.f = f;
    unsigned r = v.u + 0x7FFFu + ((v.u >> 16) & 1u);
    return (unsigned short)(r >> 16);
}

// ---------------------------------------------------------------------------
// GEMM: C[m,n] = sum_k A[m,k] * B[n,k] (+bias[n]) ; 128x128 tile, BK=32,
// 256 threads = 4 waves in 2x2, each wave 64x64 via 4x4 of 16x16x32 bf16 MFMA.
// MODE 0: write bf16 C[row*ldc+col]
// MODE 1: write bf16 transposed per-head V:  vt[((b*8+h)*64+dv)*2048 + lk]
// MODE 2: write fp32 C = val + resid[row*ldc+col]
// ABF16: A is bf16 (ushort) instead of fp32.
// ---------------------------------------------------------------------------
template<int MODE, bool ABF16>
__global__ __launch_bounds__(256)
void gemm_bt(const void* __restrict__ Aptr, int lda,
             const float* __restrict__ Bm, int ldb,
             const float* __restrict__ bias,
             const float* __restrict__ resid,
             void* __restrict__ Cout, int ldc)
{
    constexpr int LS = 40;  // 32 + 8 pad: bank-stride 20 words -> 2-way (free)
    __shared__ unsigned short As[128 * LS];
    __shared__ unsigned short Bs[128 * LS];
    const int t = threadIdx.x;
    const int lane = t & 63, w = t >> 6;
    const int wm = (w >> 1) * 64, wn = (w & 1) * 64;
    const int bm0 = blockIdx.x * 128, bn0 = blockIdx.y * 128;
    const int ar = t >> 1, ak = (t & 1) * 16;
    const int fr = lane & 15, fq = lane >> 4, fk = fq * 8;

    f4v zero = {0.f, 0.f, 0.f, 0.f};
    f4v acc[4][4];
#pragma unroll
    for (int i = 0; i < 4; i++)
#pragma unroll
        for (int j = 0; j < 4; j++) acc[i][j] = zero;

    for (int k0 = 0; k0 < E_; k0 += 32) {
        unsigned short ta[16], tb[16];
        if (ABF16) {
            const unsigned short* ag = (const unsigned short*)Aptr + (size_t)(bm0 + ar) * lda + k0 + ak;
            *(int4*)&ta[0] = *(const int4*)ag;
            *(int4*)&ta[8] = *(const int4*)(ag + 8);
        } else {
            const float* ag = (const float*)Aptr + (size_t)(bm0 + ar) * lda + k0 + ak;
#pragma unroll
            for (int u = 0; u < 16; u += 4) {
                float4 va = *(const float4*)(ag + u);
                ta[u] = f2bf(va.x); ta[u+1] = f2bf(va.y);
                ta[u+2] = f2bf(va.z); ta[u+3] = f2bf(va.w);
            }
        }
        {
            const float* bg = Bm + (size_t)(bn0 + ar) * ldb + k0 + ak;
#pragma unroll
            for (int u = 0; u < 16; u += 4) {
                float4 vb = *(const float4*)(bg + u);
                tb[u] = f2bf(vb.x); tb[u+1] = f2bf(vb.y);
                tb[u+2] = f2bf(vb.z); tb[u+3] = f2bf(vb.w);
            }
        }
        __syncthreads();
        *(int4*)&As[ar * LS + ak]     = *(int4*)&ta[0];
        *(int4*)&As[ar * LS + ak + 8] = *(int4*)&ta[8];
        *(int4*)&Bs[ar * LS + ak]     = *(int4*)&tb[0];
        *(int4*)&Bs[ar * LS + ak + 8] = *(int4*)&tb[8];
        __syncthreads();

        s8v af[4], bf[4];
#pragma unroll
        for (int i = 0; i < 4; i++) af[i] = *(const s8v*)&As[(wm + 16*i + fr) * LS + fk];
#pragma unroll
        for (int j = 0; j < 4; j++) bf[j] = *(const s8v*)&Bs[(wn + 16*j + fr) * LS + fk];
#pragma unroll
        for (int i = 0; i < 4; i++)
#pragma unroll
            for (int j = 0; j < 4; j++)
                acc[i][j] = __builtin_amdgcn_mfma_f32_16x16x32_bf16(af[i], bf[j], acc[i][j], 0, 0, 0);
    }

#pragma unroll
    for (int i = 0; i < 4; i++) {
#pragma unroll
        for (int j = 0; j < 4; j++) {
            const int col = bn0 + wn + 16*j + fr;
            const float bv = bias ? bias[col] : 0.f;
#pragma unroll
            for (int reg = 0; reg < 4; reg++) {
                const int row = bm0 + wm + 16*i + fq*4 + reg;  // C: col=lane&15, row=quad*4+reg
                float val = acc[i][j][reg] + bv;
                if (MODE == 0) {
                    ((unsigned short*)Cout)[(size_t)row * ldc + col] = f2bf(val);
                } else if (MODE == 1) {
                    const int b = row >> 11, lk = row & 2047;
                    const int h = col >> 6,  dv = col & 63;
                    ((unsigned short*)Cout)[(((size_t)(b * H_ + h) * 64 + dv) << 11) + lk] = f2bf(val);
                } else {
                    float o = val + resid[(size_t)row * ldc + col];
                    ((float*)Cout)[(size_t)row * ldc + col] = o;
                }
            }
        }
    }
}

// ---------------------------------------------------------------------------
// Attention pass 1: per (b,h, 64-q-row tile) stream K in 128-col tiles,
// compute masked scaled S via MFMA, online row max/sum -> stat_m, stat_l.
// ---------------------------------------------------------------------------
__global__ __launch_bounds__(256)
void attn_p1(const unsigned short* __restrict__ qh,
             const unsigned short* __restrict__ kh,
             const int* __restrict__ mask,
             float* __restrict__ stat_m, float* __restrict__ stat_l)
{
    __shared__ unsigned short Qs[64 * 72];
    __shared__ unsigned short Ks[128 * 72];
    const int t = threadIdx.x, lane = t & 63, w = t >> 6;
    const int q0 = blockIdx.x * 64;
    const int bh = blockIdx.y, b = bh >> 3, h = bh & 7;
    const int fr = lane & 15, fq = lane >> 4, fk = fq * 8;
    f4v zero = {0.f, 0.f, 0.f, 0.f};

    {   // stage Q tile [64 x 64] once
        const int row = t >> 2, kofs = (t & 3) * 16;
        const unsigned short* g = qh + ((size_t)(b * L_ + q0 + row) * E_ + h * 64 + kofs);
        *(int4*)&Qs[row * 72 + kofs]     = *(const int4*)g;
        *(int4*)&Qs[row * 72 + kofs + 8] = *(const int4*)(g + 8);
    }

    float m_r[4], l_r[4];
#pragma unroll
    for (int r = 0; r < 4; r++) { m_r[r] = -3e38f; l_r[r] = 0.f; }

    const size_t mbase = (size_t)b * ((size_t)L_ * L_);

    for (int kb = 0; kb < L_; kb += 128) {
        __syncthreads();
        {   // stage K tile [128 x 64]
            const int row = t >> 1, kofs = (t & 1) * 32;
            const unsigned short* g = kh + ((size_t)(b * L_ + kb + row) * E_ + h * 64 + kofs);
#pragma unroll
            for (int u = 0; u < 4; u++)
                *(int4*)&Ks[row * 72 + kofs + u * 8] = *(const int4*)(g + u * 8);
        }
        __syncthreads();

        s8v aq0 = *(const s8v*)&Qs[(w * 16 + fr) * 72 + fk];
        s8v aq1 = *(const s8v*)&Qs[(w * 16 + fr) * 72 + 32 + fk];
        f4v sv[8];
#pragma unroll
        for (int nt = 0; nt < 8; nt++) {
            s8v b0 = *(const s8v*)&Ks[(nt * 16 + fr) * 72 + fk];
            s8v b1 = *(const s8v*)&Ks[(nt * 16 + fr) * 72 + 32 + fk];
            f4v sc = zero;
            sc = __builtin_amdgcn_mfma_f32_16x16x32_bf16(aq0, b0, sc, 0, 0, 0);
            sc = __builtin_amdgcn_mfma_f32_16x16x32_bf16(aq1, b1, sc, 0, 0, 0);
            sv[nt] = sc;
        }

        float tm[4] = {-3e38f, -3e38f, -3e38f, -3e38f};
#pragma unroll
        for (int nt = 0; nt < 8; nt++)
#pragma unroll
            for (int reg = 0; reg < 4; reg++) {
                const int row = q0 + w * 16 + fq * 4 + reg;
                const int col = kb + nt * 16 + fr;
                const int mk = mask[mbase + (size_t)row * L_ + col];
                float s = mk ? NEGV : sv[nt][reg] * 0.125f;
                sv[nt][reg] = s;
                tm[reg] = fmaxf(tm[reg], s);
            }
#pragma unroll
        for (int d = 1; d < 16; d <<= 1)
#pragma unroll
            for (int reg = 0; reg < 4; reg++)
                tm[reg] = fmaxf(tm[reg], __shfl_xor(tm[reg], d));
#pragma unroll
        for (int reg = 0; reg < 4; reg++) {
            const float mn = fmaxf(m_r[reg], tm[reg]);
            const float corr = __expf(m_r[reg] - mn);
            float ps = 0.f;
#pragma unroll
            for (int nt = 0; nt < 8; nt++) ps += __expf(sv[nt][reg] - mn);
#pragma unroll
            for (int d = 1; d < 16; d <<= 1) ps += __shfl_xor(ps, d);
            l_r[reg] = l_r[reg] * corr + ps;
            m_r[reg] = mn;
        }
    }

    if (fr == 0) {
#pragma unroll
        for (int reg = 0; reg < 4; reg++) {
            const int row = q0 + w * 16 + fq * 4 + reg;
            stat_m[(size_t)bh * L_ + row] = m_r[reg];
            stat_l[(size_t)bh * L_ + row] = l_r[reg];
        }
    }
}

// ---------------------------------------------------------------------------
// Attention pass 2: recompute S, P = exp(s-m)/l, write P (fp32, nontemporal)
// to attns, round-trip P through LDS (C-layout -> A-layout), accumulate P@V.
// ---------------------------------------------------------------------------
__global__ __launch_bounds__(256)
void attn_p2(const unsigned short* __restrict__ qh,
             const unsigned short* __restrict__ kh,
             const unsigned short* __restrict__ vt,
             const int* __restrict__ mask,
             const float* __restrict__ stat_m, const float* __restrict__ stat_l,
             float* __restrict__ attns, unsigned short* __restrict__ oh)
{
    __shared__ unsigned short Qs[64 * 72];
    __shared__ unsigned short Ks[128 * 72];
    __shared__ unsigned short Vs[64 * 136];
    __shared__ unsigned short Ps[64 * 136];
    const int t = threadIdx.x, lane = t & 63, w = t >> 6;
    const int q0 = blockIdx.x * 64;
    const int bh = blockIdx.y, b = bh >> 3, h = bh & 7;
    const int fr = lane & 15, fq = lane >> 4, fk = fq * 8;
    f4v zero = {0.f, 0.f, 0.f, 0.f};

    {   // stage Q tile once
        const int row = t >> 2, kofs = (t & 3) * 16;
        const unsigned short* g = qh + ((size_t)(b * L_ + q0 + row) * E_ + h * 64 + kofs);
        *(int4*)&Qs[row * 72 + kofs]     = *(const int4*)g;
        *(int4*)&Qs[row * 72 + kofs + 8] = *(const int4*)(g + 8);
    }

    float m_r[4], rl[4];
#pragma unroll
    for (int reg = 0; reg < 4; reg++) {
        const int row = q0 + w * 16 + fq * 4 + reg;
        m_r[reg] = stat_m[(size_t)bh * L_ + row];
        rl[reg]  = 1.f / stat_l[(size_t)bh * L_ + row];
    }

    f4v o[4];
#pragma unroll
    for (int j = 0; j < 4; j++) o[j] = zero;

    const size_t mbase = (size_t)b * ((size_t)L_ * L_);
    const size_t abase = (size_t)(h * B_ + b) * ((size_t)L_ * L_);
    const int prow = w * 16 + fq * 4;  // local P row base for this lane group

    for (int kb = 0; kb < L_; kb += 128) {
        __syncthreads();
        {   // stage K tile [128 x 64]
            const int row = t >> 1, kofs = (t & 1) * 32;
            const unsigned short* g = kh + ((size_t)(b * L_ + kb + row) * E_ + h * 64 + kofs);
#pragma unroll
            for (int u = 0; u < 4; u++)
                *(int4*)&Ks[row * 72 + kofs + u * 8] = *(const int4*)(g + u * 8);
        }
        {   // stage V^T tile [64 dv x 128 k]
            const int row = t >> 2, kofs = (t & 3) * 32;
            const unsigned short* g = vt + ((size_t)(b * H_ + h) * 64 + row) * L_ + kb + kofs;
#pragma unroll
            for (int u = 0; u < 4; u++)
                *(int4*)&Vs[row * 136 + kofs + u * 8] = *(const int4*)(g + u * 8);
        }
        __syncthreads();

        s8v aq0 = *(const s8v*)&Qs[(w * 16 + fr) * 72 + fk];
        s8v aq1 = *(const s8v*)&Qs[(w * 16 + fr) * 72 + 32 + fk];
#pragma unroll
        for (int nt = 0; nt < 8; nt++) {
            s8v b0 = *(const s8v*)&Ks[(nt * 16 + fr) * 72 + fk];
            s8v b1 = *(const s8v*)&Ks[(nt * 16 + fr) * 72 + 32 + fk];
            f4v sc = zero;
            sc = __builtin_amdgcn_mfma_f32_16x16x32_bf16(aq0, b0, sc, 0, 0, 0);
            sc = __builtin_amdgcn_mfma_f32_16x16x32_bf16(aq1, b1, sc, 0, 0, 0);
#pragma unroll
            for (int reg = 0; reg < 4; reg++) {
                const int row = q0 + prow + reg;
                const int col = kb + nt * 16 + fr;
                const int mk = mask[mbase + (size_t)row * L_ + col];
                float s = mk ? NEGV : sc[reg] * 0.125f;
                float p = __expf(s - m_r[reg]) * rl[reg];
                __builtin_nontemporal_store(p, &attns[abase + (size_t)row * L_ + col]);
                Ps[(prow + reg) * 136 + nt * 16 + fr] = f2bf(p);
            }
        }
        __syncthreads();

        // PV: A = P (16 rows per wave), B = V^T; K-tile of 128 = 4 MFMA k-steps
#pragma unroll
        for (int ks = 0; ks < 4; ks++) {
            s8v pa = *(const s8v*)&Ps[(w * 16 + fr) * 136 + ks * 32 + fk];
#pragma unroll
            for (int j = 0; j < 4; j++) {
                s8v vb = *(const s8v*)&Vs[(j * 16 + fr) * 136 + ks * 32 + fk];
                o[j] = __builtin_amdgcn_mfma_f32_16x16x32_bf16(pa, vb, o[j], 0, 0, 0);
            }
        }
    }

    // write heads output [B, L, H*DV] bf16
#pragma unroll
    for (int j = 0; j < 4; j++)
#pragma unroll
        for (int reg = 0; reg < 4; reg++) {
            const int row = q0 + prow + reg;
            const int col = h * 64 + j * 16 + fr;
            oh[(size_t)(b * L_ + row) * (H_ * D_) + col] = f2bf(o[j][reg]);
        }
}

// ---------------------------------------------------------------------------
// LayerNorm: one wave per row of 512.
// ---------------------------------------------------------------------------
__global__ __launch_bounds__(256)
void ln_k(const float* __restrict__ x, const float* __restrict__ gamma,
          const float* __restrict__ beta, float* __restrict__ out)
{
    const int t = threadIdx.x, lane = t & 63, w = t >> 6;
    const int row = blockIdx.x * 4 + w;
    const float* xr = x + (size_t)row * E_;
    const int cb = lane * 8;
    float4 a = *(const float4*)(xr + cb);
    float4 c = *(const float4*)(xr + cb + 4);
    float s  = a.x + a.y + a.z + a.w + c.x + c.y + c.z + c.w;
    float s2 = a.x*a.x + a.y*a.y + a.z*a.z + a.w*a.w
             + c.x*c.x + c.y*c.y + c.z*c.z + c.w*c.w;
#pragma unroll
    for (int d = 1; d < 64; d <<= 1) { s += __shfl_xor(s, d); s2 += __shfl_xor(s2, d); }
    const float mu  = s * (1.f / E_);
    const float var = s2 * (1.f / E_) - mu * mu;
    const float rs  = rsqrtf(var + 1e-5f);
    float4 g0 = *(const float4*)(gamma + cb), g1 = *(const float4*)(gamma + cb + 4);
    float4 b0 = *(const float4*)(beta + cb),  b1 = *(const float4*)(beta + cb + 4);
    float4 o0, o1;
    o0.x = (a.x - mu) * rs * g0.x + b0.x;  o0.y = (a.y - mu) * rs * g0.y + b0.y;
    o0.z = (a.z - mu) * rs * g0.z + b0.z;  o0.w = (a.w - mu) * rs * g0.w + b0.w;
    o1.x = (c.x - mu) * rs * g1.x + b1.x;  o1.y = (c.y - mu) * rs * g1.y + b1.y;
    o1.z = (c.z - mu) * rs * g1.z + b1.z;  o1.w = (c.w - mu) * rs * g1.w + b1.w;
    float* orow = out + (size_t)row * E_;
    *(float4*)(orow + cb)     = o0;
    *(float4*)(orow + cb + 4) = o1;
}

// ---------------------------------------------------------------------------
extern "C" void kernel_launch(void* const* d_in, const int* in_sizes, int n_in,
                              void* d_out, int out_size, void* d_ws, size_t ws_size,
                              hipStream_t stream)
{
    const float* q     = (const float*)d_in[0];
    const float* k     = (const float*)d_in[1];
    const float* v     = (const float*)d_in[2];
    const int*   mask  = (const int*)d_in[3];
    const float* Wq    = (const float*)d_in[4];
    const float* bq    = (const float*)d_in[5];
    const float* Wk    = (const float*)d_in[6];
    const float* bk    = (const float*)d_in[7];
    const float* Wv    = (const float*)d_in[8];
    const float* bv    = (const float*)d_in[9];
    const float* Wfc   = (const float*)d_in[10];
    const float* bfc   = (const float*)d_in[11];
    const float* gamma = (const float*)d_in[12];
    const float* beta  = (const float*)d_in[13];

    char* ws = (char*)d_ws;
    unsigned short* qh  = (unsigned short*)(ws);                    //  0 .. 8 MB
    unsigned short* kh  = (unsigned short*)(ws + (8u  << 20));      //  8 ..16 MB
    unsigned short* vt  = (unsigned short*)(ws + (16u << 20));      // 16 ..24 MB
    unsigned short* oh  = (unsigned short*)(ws + (24u << 20));      // 24 ..32 MB
    float* statm        = (float*)(ws + (32u << 20));               // 256 KB
    float* statl        = (float*)(ws + (32u << 20) + (256u << 10));// 256 KB
    float* xbuf         = (float*)(ws);  // reuses qh/kh region (dead by then)

    float* outputs = (float*)d_out;
    float* attns   = outputs + (size_t)B_ * L_ * E_;

    dim3 gg(64, 4), blk(256);
    gemm_bt<0, false><<<gg, blk, 0, stream>>>(q, E_, Wq, E_, bq, nullptr, qh, H_ * D_);
    gemm_bt<0, false><<<gg, blk, 0, stream>>>(k, E_, Wk, E_, bk, nullptr, kh, H_ * D_);
    gemm_bt<1, false><<<gg, blk, 0, stream>>>(v, E_, Wv, E_, bv, nullptr, vt, 0);

    attn_p1<<<dim3(32, 32), blk, 0, stream>>>(qh, kh, mask, statm, statl);
    attn_p2<<<dim3(32, 32), blk, 0, stream>>>(qh, kh, vt, mask, statm, statl, attns, oh);

    gemm_bt<2, true><<<gg, blk, 0, stream>>>(oh, H_ * D_, Wfc, H_ * D_, bfc, q, xbuf, E_);
    ln_k<<<2048, blk, 0, stream>>>(xbuf, gamma, beta, outputs);
}